// Round 22
// baseline (6954.327 us; speedup 1.0000x reference)
//
#include <hip/hip_runtime.h>
#include <math.h>

#define TT 2048
#define BB 32
#define HH 512

// ---------------- input-projection GEMM: OUT[r,:] = X[r,:]@W + bias ----------------
template<int K>
__global__ void __launch_bounds__(256)
ih_gemm(const float* X, const float* __restrict__ W,
        const float* __restrict__ bias, float* OUT)
{
    __shared__ float xt[32][K];
    const int wg  = (int)blockIdx.x;
    const int tid = (int)threadIdx.x;
    const long row0 = (long)wg * 32;

    {   // stage 32 rows of X (coalesced float4)
        const float4* Xv = (const float4*)(X + row0 * K);
        float4* xtv = (float4*)(&xt[0][0]);
        const int n4 = 8 * K;
        for (int i = tid; i < n4; i += 256) xtv[i] = Xv[i];
    }
    __syncthreads();

    const int j2 = tid * 2;
    float acc0[32], acc1[32];
    #pragma unroll
    for (int r = 0; r < 32; ++r) { acc0[r] = 0.f; acc1[r] = 0.f; }

    for (int k = 0; k < K; k += 4) {
        const float2 w0 = *(const float2*)&W[(k+0)*HH + j2];
        const float2 w1 = *(const float2*)&W[(k+1)*HH + j2];
        const float2 w2 = *(const float2*)&W[(k+2)*HH + j2];
        const float2 w3 = *(const float2*)&W[(k+3)*HH + j2];
        #pragma unroll
        for (int r = 0; r < 32; ++r) {
            const float4 xv = *(const float4*)&xt[r][k];
            acc0[r] += xv.x*w0.x + xv.y*w1.x + xv.z*w2.x + xv.w*w3.x;
            acc1[r] += xv.x*w0.y + xv.y*w1.y + xv.z*w2.y + xv.w*w3.y;
        }
    }
    const float2 bv = *(const float2*)&bias[j2];
    #pragma unroll
    for (int r = 0; r < 32; ++r) {
        float2 o; o.x = acc0[r] + bv.x; o.y = acc1[r] + bv.y;
        *(float2*)&OUT[(row0 + r) * HH + j2] = o;
    }
}

// ---------------- fused 2-layer recurrence, TWO chains per 8-WG group ----------------
// r17 protocol per chain (PASSED; tag-chain + parity-LDS proofs unchanged per chain),
// interleaved A/B: W registers are batch-invariant, so the same 192 pinned VGPRs
// serve both chains. Each chain's exposed publish->poll latency ages under the OTHER
// chain's compute: all four samples (p3sA/B, p2sA/B) have age >= ~0.5-0.9us >= V at
// their read, issued at the r17-proven point (right after a P3 resolve). Fallback =
// proven pollv on every path; correctness never depends on sample timing.
// Grid: 16 pairs x 8 WGs = 128 WGs (latency-bound; idle CUs are free).
static __device__ __forceinline__ float tanhx(float s) {
    const float e = __expf(2.0f * s);
    return 1.0f - 2.0f / (e + 1.0f);
}
static __device__ __forceinline__ void pub(unsigned long long* p, unsigned tag, float v) {
    __hip_atomic_store(p, ((unsigned long long)tag << 32) | (unsigned long long)__float_as_uint(v),
                       __ATOMIC_RELAXED, __HIP_MEMORY_SCOPE_AGENT);
}
static __device__ __forceinline__ float pollv(unsigned long long* p, unsigned want) {
    unsigned long long pk = __hip_atomic_load(p, __ATOMIC_RELAXED, __HIP_MEMORY_SCOPE_AGENT);
    while ((unsigned)(pk >> 32) != want)
        pk = __hip_atomic_load(p, __ATOMIC_RELAXED, __HIP_MEMORY_SCOPE_AGENT);
    return __uint_as_float((unsigned)(pk & 0xffffffffu));
}
static __device__ __forceinline__ unsigned long long samp(unsigned long long* p) {
    return __hip_atomic_load(p, __ATOMIC_RELAXED, __HIP_MEMORY_SCOPE_AGENT);
}

__global__ void __attribute__((amdgpu_flat_work_group_size(512, 512),
                               amdgpu_waves_per_eu(2, 2)))
fused_recur2(const float* __restrict__ Whh0, const float* __restrict__ Wih1,
             const float* __restrict__ Whh1, const float* __restrict__ b1,
             float* __restrict__ seq, float* __restrict__ hTout,
             unsigned long long* __restrict__ hb0, unsigned long long* __restrict__ hb1)
{
    __shared__ float lds_aA[2][8][64], lds_bA[2][8][64];
    __shared__ float lds_aB[2][8][64], lds_bB[2][8][64];
    const int bid  = (int)blockIdx.x;
    const int cA   = bid & 15;      // pair id: chains cA and cA+16
    const int cB   = cA + 16;
    const int x    = bid >> 4;      // col-slice 0..7
    const int tid  = (int)threadIdx.x;
    const int lane = tid & 63;
    const int w    = tid >> 6;      // wave id == k-group
    const int J    = (x << 6) + lane;
    const long wb  = (long)(w << 6) * HH + J;   // &M[(w*64+kk)*HH + J], kk stride HH
    const int slot = (w << 6) + lane;           // my poll slot within a parity page

    // ---- three W slices, 48 named float4s (192 VGPRs), pinned; SHARED by A and B ----
    float4 wa0,wa1,wa2,wa3,wa4,wa5,wa6,wa7,wa8,wa9,wa10,wa11,wa12,wa13,wa14,wa15;  // Whh0
    float4 wi0,wi1,wi2,wi3,wi4,wi5,wi6,wi7,wi8,wi9,wi10,wi11,wi12,wi13,wi14,wi15;  // Wih1
    float4 wh0,wh1,wh2,wh3,wh4,wh5,wh6,wh7,wh8,wh9,wh10,wh11,wh12,wh13,wh14,wh15;  // Whh1
#define LD1(P, M, q) do { \
        P##q.x = M[wb + (4*q+0)*HH]; P##q.y = M[wb + (4*q+1)*HH]; \
        P##q.z = M[wb + (4*q+2)*HH]; P##q.w = M[wb + (4*q+3)*HH]; } while (0)
#define LD16(P, M) do { LD1(P,M,0); LD1(P,M,1); LD1(P,M,2); LD1(P,M,3); \
        LD1(P,M,4); LD1(P,M,5); LD1(P,M,6); LD1(P,M,7); LD1(P,M,8); LD1(P,M,9); \
        LD1(P,M,10); LD1(P,M,11); LD1(P,M,12); LD1(P,M,13); LD1(P,M,14); LD1(P,M,15); } while (0)
    LD16(wa, Whh0); LD16(wi, Wih1); LD16(wh, Whh1);
#undef LD16
#undef LD1
#define PIN1(P, q) asm volatile("" : "+v"(P##q.x), "+v"(P##q.y), "+v"(P##q.z), "+v"(P##q.w))
#define PIN16(P) do { PIN1(P,0); PIN1(P,1); PIN1(P,2); PIN1(P,3); PIN1(P,4); PIN1(P,5); \
        PIN1(P,6); PIN1(P,7); PIN1(P,8); PIN1(P,9); PIN1(P,10); PIN1(P,11); PIN1(P,12); \
        PIN1(P,13); PIN1(P,14); PIN1(P,15); } while (0)
    PIN16(wa); PIN16(wi); PIN16(wh);
#undef PIN16
#undef PIN1

    unsigned long long* hbc0A = hb0 + cA * (2 * HH);
    unsigned long long* hbc1A = hb1 + cA * (2 * HH);
    unsigned long long* hbc0B = hb0 + cB * (2 * HH);
    unsigned long long* hbc1B = hb1 + cB * (2 * HH);
    float* rowA = seq + (long)cA * TT * HH;
    float* rowB = seq + (long)cB * TT * HH;

    float preA = 0.f, preB = 0.f, b1v = 0.f;
    if (tid < 64) { preA = rowA[J]; preB = rowB[J]; }      // wave0: layer-0 tails
    if (tid >= 64 && tid < 128) b1v = b1[J];               // wave1: layer-1 tails

    // prologue: h0[0] = tanh(pre0[0]) for both chains; publish tag 1 (slot 0)
    if (tid < 64) {
        pub(hbc0A + J, 1u, tanhx(preA));
        pub(hbc0B + J, 1u, tanhx(preB));
        preA = rowA[HH + J];
        preB = rowB[HH + J];
    }
    float h1A = 0.f, h1B = 0.f;
    unsigned long long p3sA = 0, p3sB = 0, p2sA = 0, p2sB = 0;

#define BCA0(i) __uint_as_float(__builtin_amdgcn_readlane(h0bitsA, (i)))
#define BCA1(i) __uint_as_float(__builtin_amdgcn_readlane(h1bitsA, (i)))
#define BCB0(i) __uint_as_float(__builtin_amdgcn_readlane(h0bitsB, (i)))
#define BCB1(i) __uint_as_float(__builtin_amdgcn_readlane(h1bitsB, (i)))

    for (int t = 0; t < TT; ++t) {
        // ================= A phase =================
        // P3_A: resolve h0A[t] (tag t+1): sample from last iter's B-top, or pollv.
        float h0Av;
        if ((unsigned)(p3sA >> 32) == (unsigned)(t + 1))
            h0Av = __uint_as_float((unsigned)p3sA);
        else
            h0Av = pollv(hbc0A + ((t & 1) << 9) + slot, (unsigned)(t + 1));
        const unsigned h0bitsA = __float_as_uint(h0Av);

        // issue samples (r17-proven point): p2sA (h1A[t-1], aged a full B-phase) and
        // p3sB (h0B[t], published in prev iter's C1_B). Both return before bar1_A.
        if (t > 0) p2sA = samp(hbc1A + (((t - 1) & 1) << 9) + slot);
        p3sB = samp(hbc0B + ((t & 1) << 9) + slot);

        if (t + 1 < TT) {   // C1_A
            float a0 = 0.f, a1 = 0.f, a2 = 0.f, a3 = 0.f;
#define MACA(q) do { a0 = fmaf(BCA0(4*q+0), wa##q.x, a0); a1 = fmaf(BCA0(4*q+1), wa##q.y, a1); \
                     a2 = fmaf(BCA0(4*q+2), wa##q.z, a2); a3 = fmaf(BCA0(4*q+3), wa##q.w, a3); } while (0)
            MACA(0); MACA(1); MACA(2); MACA(3); MACA(4); MACA(5); MACA(6); MACA(7);
            MACA(8); MACA(9); MACA(10); MACA(11); MACA(12); MACA(13); MACA(14); MACA(15);
#undef MACA
            lds_aA[(t + 1) & 1][w][lane] = (a0 + a1) + (a2 + a3);
            __syncthreads();
            if (tid < 64) {
                float s = preA;
                #pragma unroll
                for (int q = 0; q < 8; ++q) s += lds_aA[(t + 1) & 1][q][lane];
                const float hv = tanhx(s);
                pub(hbc0A + (((t + 1) & 1) << 9) + J, (unsigned)(t + 2), hv);
                if (t + 2 < TT) preA = rowA[(long)(t + 2) * HH + J];
                if (t + 1 == TT - 1) hTout[(cA << 9) + J] = hv;
            }
        }
        if (t > 0) {
            if ((unsigned)(p2sA >> 32) == (unsigned)t)
                h1A = __uint_as_float((unsigned)p2sA);
            else
                h1A = pollv(hbc1A + (((t - 1) & 1) << 9) + slot, (unsigned)t);
        }
        const unsigned h1bitsA = __float_as_uint(h1A);
        {   // C2_A
            float a0 = 0.f, a1 = 0.f, a2 = 0.f, a3 = 0.f;
#define MACI(q) do { a0 = fmaf(BCA0(4*q+0), wi##q.x, a0); a1 = fmaf(BCA0(4*q+1), wi##q.y, a1); \
                     a2 = fmaf(BCA0(4*q+2), wi##q.z, a2); a3 = fmaf(BCA0(4*q+3), wi##q.w, a3); } while (0)
#define MACH(q) do { a0 = fmaf(BCA1(4*q+0), wh##q.x, a0); a1 = fmaf(BCA1(4*q+1), wh##q.y, a1); \
                     a2 = fmaf(BCA1(4*q+2), wh##q.z, a2); a3 = fmaf(BCA1(4*q+3), wh##q.w, a3); } while (0)
            MACI(0); MACI(1); MACI(2); MACI(3); MACI(4); MACI(5); MACI(6); MACI(7);
            MACI(8); MACI(9); MACI(10); MACI(11); MACI(12); MACI(13); MACI(14); MACI(15);
            MACH(0); MACH(1); MACH(2); MACH(3); MACH(4); MACH(5); MACH(6); MACH(7);
            MACH(8); MACH(9); MACH(10); MACH(11); MACH(12); MACH(13); MACH(14); MACH(15);
#undef MACH
#undef MACI
            lds_bA[t & 1][w][lane] = (a0 + a1) + (a2 + a3);
            __syncthreads();
            if (tid >= 64 && tid < 128) {
                float s2 = b1v;
                #pragma unroll
                for (int q = 0; q < 8; ++q) s2 += lds_bA[t & 1][q][lane];
                const float h1v = tanhx(s2);
                rowA[(long)t * HH + J] = h1v;
                if (t + 1 < TT) pub(hbc1A + ((t & 1) << 9) + J, (unsigned)(t + 1), h1v);
                else hTout[(BB << 9) + (cA << 9) + J] = h1v;
            }
        }

        // ================= B phase =================
        float h0Bv;
        if ((unsigned)(p3sB >> 32) == (unsigned)(t + 1))
            h0Bv = __uint_as_float((unsigned)p3sB);
        else
            h0Bv = pollv(hbc0B + ((t & 1) << 9) + slot, (unsigned)(t + 1));
        const unsigned h0bitsB = __float_as_uint(h0Bv);

        // issue samples: p2sB (h1B[t-1], aged a full A-phase) and p3sA for next iter
        // (h0A[t+1], published in C1_A above, age ~C2_A by read time).
        if (t > 0) p2sB = samp(hbc1B + (((t - 1) & 1) << 9) + slot);
        if (t + 1 < TT) p3sA = samp(hbc0A + (((t + 1) & 1) << 9) + slot);

        if (t + 1 < TT) {   // C1_B
            float a0 = 0.f, a1 = 0.f, a2 = 0.f, a3 = 0.f;
#define MACA(q) do { a0 = fmaf(BCB0(4*q+0), wa##q.x, a0); a1 = fmaf(BCB0(4*q+1), wa##q.y, a1); \
                     a2 = fmaf(BCB0(4*q+2), wa##q.z, a2); a3 = fmaf(BCB0(4*q+3), wa##q.w, a3); } while (0)
            MACA(0); MACA(1); MACA(2); MACA(3); MACA(4); MACA(5); MACA(6); MACA(7);
            MACA(8); MACA(9); MACA(10); MACA(11); MACA(12); MACA(13); MACA(14); MACA(15);
#undef MACA
            lds_aB[(t + 1) & 1][w][lane] = (a0 + a1) + (a2 + a3);
            __syncthreads();
            if (tid < 64) {
                float s = preB;
                #pragma unroll
                for (int q = 0; q < 8; ++q) s += lds_aB[(t + 1) & 1][q][lane];
                const float hv = tanhx(s);
                pub(hbc0B + (((t + 1) & 1) << 9) + J, (unsigned)(t + 2), hv);
                if (t + 2 < TT) preB = rowB[(long)(t + 2) * HH + J];
                if (t + 1 == TT - 1) hTout[(cB << 9) + J] = hv;
            }
        }
        if (t > 0) {
            if ((unsigned)(p2sB >> 32) == (unsigned)t)
                h1B = __uint_as_float((unsigned)p2sB);
            else
                h1B = pollv(hbc1B + (((t - 1) & 1) << 9) + slot, (unsigned)t);
        }
        const unsigned h1bitsB = __float_as_uint(h1B);
        {   // C2_B
            float a0 = 0.f, a1 = 0.f, a2 = 0.f, a3 = 0.f;
#define MACI(q) do { a0 = fmaf(BCB0(4*q+0), wi##q.x, a0); a1 = fmaf(BCB0(4*q+1), wi##q.y, a1); \
                     a2 = fmaf(BCB0(4*q+2), wi##q.z, a2); a3 = fmaf(BCB0(4*q+3), wi##q.w, a3); } while (0)
#define MACH(q) do { a0 = fmaf(BCB1(4*q+0), wh##q.x, a0); a1 = fmaf(BCB1(4*q+1), wh##q.y, a1); \
                     a2 = fmaf(BCB1(4*q+2), wh##q.z, a2); a3 = fmaf(BCB1(4*q+3), wh##q.w, a3); } while (0)
            MACI(0); MACI(1); MACI(2); MACI(3); MACI(4); MACI(5); MACI(6); MACI(7);
            MACI(8); MACI(9); MACI(10); MACI(11); MACI(12); MACI(13); MACI(14); MACI(15);
            MACH(0); MACH(1); MACH(2); MACH(3); MACH(4); MACH(5); MACH(6); MACH(7);
            MACH(8); MACH(9); MACH(10); MACH(11); MACH(12); MACH(13); MACH(14); MACH(15);
#undef MACH
#undef MACI
            lds_bB[t & 1][w][lane] = (a0 + a1) + (a2 + a3);
            __syncthreads();
            if (tid >= 64 && tid < 128) {
                float s2 = b1v;
                #pragma unroll
                for (int q = 0; q < 8; ++q) s2 += lds_bB[t & 1][q][lane];
                const float h1v = tanhx(s2);
                rowB[(long)t * HH + J] = h1v;
                if (t + 1 < TT) pub(hbc1B + ((t & 1) << 9) + J, (unsigned)(t + 1), h1v);
                else hTout[(BB << 9) + (cB << 9) + J] = h1v;
            }
        }
    }
#undef BCB1
#undef BCB0
#undef BCA1
#undef BCA0
}

extern "C" void kernel_launch(void* const* d_in, const int* in_sizes, int n_in,
                              void* d_out, int out_size, void* d_ws, size_t ws_size,
                              hipStream_t stream) {
    const float* x    = (const float*)d_in[0];
    const float* Wih0 = (const float*)d_in[1];
    const float* Whh0 = (const float*)d_in[2];
    const float* b0   = (const float*)d_in[3];
    const float* Wih1 = (const float*)d_in[4];
    const float* Whh1 = (const float*)d_in[5];
    const float* b1   = (const float*)d_in[6];

    float* out = (float*)d_out;                       // [B,T,H] (h1 seq) + [2,B,H] (hT)
    float* hT  = out + (size_t)BB * TT * HH;

    // ws: hb0 (256K) + hb1 (256K). memset each call (replays reuse ws; stale tags
    // would alias wanted tags).
    unsigned long long* hb0 = (unsigned long long*)d_ws;
    unsigned long long* hb1 = hb0 + (size_t)BB * 2 * HH;
    (void)hipMemsetAsync(d_ws, 0, (size_t)2 * BB * 2 * HH * sizeof(unsigned long long), stream);

    // 1) pre0 = x @ W_ih0 + b0  -> d_out main region (consumed in-place by fused_recur2)
    ih_gemm<256><<<dim3((BB * TT) / 32), dim3(256), 0, stream>>>(x, Wih0, b0, out);
    // 2) fused 2-layer recurrence, 2 chains per 8-WG group: 16 pairs x 8 = 128 WGs
    fused_recur2<<<dim3(128), dim3(512), 0, stream>>>(Whh0, Wih1, Whh1, b1,
                                                      out, hT, hb0, hb1);
}

// Round 23
// 3684.372 us; speedup vs baseline: 1.8875x; 1.8875x over previous
//
#include <hip/hip_runtime.h>
#include <math.h>

#define TT 2048
#define BB 32
#define HH 512

// ---------------- input-projection GEMM: OUT[r,:] = X[r,:]@W + bias ----------------
template<int K>
__global__ void __launch_bounds__(256)
ih_gemm(const float* X, const float* __restrict__ W,
        const float* __restrict__ bias, float* OUT)
{
    __shared__ float xt[32][K];
    const int wg  = (int)blockIdx.x;
    const int tid = (int)threadIdx.x;
    const long row0 = (long)wg * 32;

    {   // stage 32 rows of X (coalesced float4)
        const float4* Xv = (const float4*)(X + row0 * K);
        float4* xtv = (float4*)(&xt[0][0]);
        const int n4 = 8 * K;
        for (int i = tid; i < n4; i += 256) xtv[i] = Xv[i];
    }
    __syncthreads();

    const int j2 = tid * 2;
    float acc0[32], acc1[32];
    #pragma unroll
    for (int r = 0; r < 32; ++r) { acc0[r] = 0.f; acc1[r] = 0.f; }

    for (int k = 0; k < K; k += 4) {
        const float2 w0 = *(const float2*)&W[(k+0)*HH + j2];
        const float2 w1 = *(const float2*)&W[(k+1)*HH + j2];
        const float2 w2 = *(const float2*)&W[(k+2)*HH + j2];
        const float2 w3 = *(const float2*)&W[(k+3)*HH + j2];
        #pragma unroll
        for (int r = 0; r < 32; ++r) {
            const float4 xv = *(const float4*)&xt[r][k];
            acc0[r] += xv.x*w0.x + xv.y*w1.x + xv.z*w2.x + xv.w*w3.x;
            acc1[r] += xv.x*w0.y + xv.y*w1.y + xv.z*w2.y + xv.w*w3.y;
        }
    }
    const float2 bv = *(const float2*)&bias[j2];
    #pragma unroll
    for (int r = 0; r < 32; ++r) {
        float2 o; o.x = acc0[r] + bv.x; o.y = acc1[r] + bv.y;
        *(float2*)&OUT[(row0 + r) * HH + j2] = o;
    }
}

// ---------------- fused 2-layer persistent recurrence (r17/r20 optimum) ----------------
// Best measured configuration (r17: 3666us total; r20 reproduction: 3697us).
// Structure: 8 WGs/chain, wave w = k-group; W slices (Whh0/Wih1/Whh1) in 192 pinned
// arch VGPRs (waves_per_eu(2,2) clamps the allocator's occupancy target — without it
// the pins spill, r2-r7); per-chain r9 schedule {P3 -> C1 -> P2 -> C2}; 8B relaxed
// agent-scope {tag|f32} atomics double-buffered by parity (no fences — r1's killer);
// parity-LDS partials (r3's WAR fix); EARLY P2 sample issued right after P3 success
// (age ~0.6us >= V -> hit; the single confirmed comm win, r17: -0.6ms); tail1 on
// wave0, tail2 on wave1 (r20, neutral-safe).
// Floor evidence: cycle = producer-path (~0.7us) + agent-visibility V (~0.9-1.0us);
// V-reduction (r15/r16/r18/r21) and V-amortization (r22) all regressed.
static __device__ __forceinline__ float tanhx(float s) {
    const float e = __expf(2.0f * s);
    return 1.0f - 2.0f / (e + 1.0f);
}
static __device__ __forceinline__ void pub(unsigned long long* p, unsigned tag, float v) {
    __hip_atomic_store(p, ((unsigned long long)tag << 32) | (unsigned long long)__float_as_uint(v),
                       __ATOMIC_RELAXED, __HIP_MEMORY_SCOPE_AGENT);
}
static __device__ __forceinline__ float pollv(unsigned long long* p, unsigned want) {
    unsigned long long pk = __hip_atomic_load(p, __ATOMIC_RELAXED, __HIP_MEMORY_SCOPE_AGENT);
    while ((unsigned)(pk >> 32) != want)
        pk = __hip_atomic_load(p, __ATOMIC_RELAXED, __HIP_MEMORY_SCOPE_AGENT);
    return __uint_as_float((unsigned)(pk & 0xffffffffu));
}

__global__ void __attribute__((amdgpu_flat_work_group_size(512, 512),
                               amdgpu_waves_per_eu(2, 2)))
fused_recur(const float* __restrict__ Whh0, const float* __restrict__ Wih1,
            const float* __restrict__ Whh1, const float* __restrict__ b1,
            float* __restrict__ seq, float* __restrict__ hTout,
            unsigned long long* __restrict__ hb0, unsigned long long* __restrict__ hb1)
{
    __shared__ float lds_a[2][8][64];
    __shared__ float lds_b[2][8][64];
    const int bid  = (int)blockIdx.x;
    const int c    = bid & 31;      // chain; 8 slices of chain c share bid%8
    const int x    = bid >> 5;      // col-slice 0..7
    const int tid  = (int)threadIdx.x;
    const int lane = tid & 63;
    const int w    = tid >> 6;      // wave id == k-group
    const int J    = (x << 6) + lane;
    const long wb  = (long)(w << 6) * HH + J;   // &M[(w*64+kk)*HH + J], kk stride HH

    // ---- three W slices, 48 named float4s (192 VGPRs), pinned ----
    float4 wa0,wa1,wa2,wa3,wa4,wa5,wa6,wa7,wa8,wa9,wa10,wa11,wa12,wa13,wa14,wa15;  // Whh0
    float4 wi0,wi1,wi2,wi3,wi4,wi5,wi6,wi7,wi8,wi9,wi10,wi11,wi12,wi13,wi14,wi15;  // Wih1
    float4 wh0,wh1,wh2,wh3,wh4,wh5,wh6,wh7,wh8,wh9,wh10,wh11,wh12,wh13,wh14,wh15;  // Whh1
#define LD1(P, M, q) do { \
        P##q.x = M[wb + (4*q+0)*HH]; P##q.y = M[wb + (4*q+1)*HH]; \
        P##q.z = M[wb + (4*q+2)*HH]; P##q.w = M[wb + (4*q+3)*HH]; } while (0)
#define LD16(P, M) do { LD1(P,M,0); LD1(P,M,1); LD1(P,M,2); LD1(P,M,3); \
        LD1(P,M,4); LD1(P,M,5); LD1(P,M,6); LD1(P,M,7); LD1(P,M,8); LD1(P,M,9); \
        LD1(P,M,10); LD1(P,M,11); LD1(P,M,12); LD1(P,M,13); LD1(P,M,14); LD1(P,M,15); } while (0)
    LD16(wa, Whh0); LD16(wi, Wih1); LD16(wh, Whh1);
#undef LD16
#undef LD1
#define PIN1(P, q) asm volatile("" : "+v"(P##q.x), "+v"(P##q.y), "+v"(P##q.z), "+v"(P##q.w))
#define PIN16(P) do { PIN1(P,0); PIN1(P,1); PIN1(P,2); PIN1(P,3); PIN1(P,4); PIN1(P,5); \
        PIN1(P,6); PIN1(P,7); PIN1(P,8); PIN1(P,9); PIN1(P,10); PIN1(P,11); PIN1(P,12); \
        PIN1(P,13); PIN1(P,14); PIN1(P,15); } while (0)
    PIN16(wa); PIN16(wi); PIN16(wh);
#undef PIN16
#undef PIN1

    unsigned long long* hbc0 = hb0 + c * (2 * HH);   // [2][512] packed {tag|val}
    unsigned long long* hbc1 = hb1 + c * (2 * HH);
    float* rowbase = seq + (long)c * TT * HH;        // pre0 in, h1 out (in-place)

    float pre_cur = 0.f, b1v = 0.f;
    if (tid < 64) pre_cur = rowbase[J];              // wave0: layer-0 tail state
    if (tid >= 64 && tid < 128) b1v = b1[J];         // wave1: layer-1 tail state

    // prologue: h0[0] = tanh(pre0[0] + 0); publish tag 1 (slot 0)
    if (tid < 64) {
        const float hv = tanhx(pre_cur);
        pub(hbc0 + J, 1u, hv);
        pre_cur = rowbase[HH + J];                   // pre0[1]
    }
    float h1reg = 0.f;

#define BC0(i) __uint_as_float(__builtin_amdgcn_readlane(h0bits, (i)))
#define BC1(i) __uint_as_float(__builtin_amdgcn_readlane(h1bits, (i)))

    for (int t = 0; t < TT; ++t) {
        // P3: poll h0[t] (tag t+1, slot t&1) — the one real RTT wait per super-step
        const float h0new = pollv(hbc0 + ((t & 1) << 9) + (w << 6) + lane, (unsigned)(t + 1));
        const unsigned h0bits = __float_as_uint(h0new);

        // EARLY P2 sample (r17 placement: after P3 success -> age >= V -> hit).
        unsigned long long* p2slot = hbc1 + (((t - 1) & 1) << 9) + (w << 6) + lane;
        unsigned long long p2s = 0;
        if (t > 0)
            p2s = __hip_atomic_load(p2slot, __ATOMIC_RELAXED, __HIP_MEMORY_SCOPE_AGENT);

        if (t + 1 < TT) {   // C1(t+1): layer-0 step — the critical chain
            float a0 = 0.f, a1 = 0.f, a2 = 0.f, a3 = 0.f;
#define MACA(q) do { a0 = fmaf(BC0(4*q+0), wa##q.x, a0); a1 = fmaf(BC0(4*q+1), wa##q.y, a1); \
                     a2 = fmaf(BC0(4*q+2), wa##q.z, a2); a3 = fmaf(BC0(4*q+3), wa##q.w, a3); } while (0)
            MACA(0); MACA(1); MACA(2); MACA(3); MACA(4); MACA(5); MACA(6); MACA(7);
            MACA(8); MACA(9); MACA(10); MACA(11); MACA(12); MACA(13); MACA(14); MACA(15);
#undef MACA
            lds_a[(t + 1) & 1][w][lane] = (a0 + a1) + (a2 + a3);
            __syncthreads();   // bar1
            if (tid < 64) {    // tail1 (wave0): layer-0 reduce + publish
                float s = pre_cur;
                #pragma unroll
                for (int q = 0; q < 8; ++q) s += lds_a[(t + 1) & 1][q][lane];
                const float hv = tanhx(s);
                pub(hbc0 + (((t + 1) & 1) << 9) + J, (unsigned)(t + 2), hv);  // publish ASAP
                if (t + 2 < TT) pre_cur = rowbase[(long)(t + 2) * HH + J];
                if (t + 1 == TT - 1) hTout[(c << 9) + J] = hv;                // hT layer 0
            }
        }

        // P2 resolve: common case = early sample already tagged; miss -> fallback.
        if (t > 0) {
            if ((unsigned)(p2s >> 32) == (unsigned)t)
                h1reg = __uint_as_float((unsigned)(p2s & 0xffffffffu));
            else
                h1reg = pollv(p2slot, (unsigned)t);
        }
        const unsigned h1bits = __float_as_uint(h1reg);

        // C2(t): layer-1 step; tail2 on wave1 (wave0 exits bar2 straight to next P3)
        {
            float a0 = 0.f, a1 = 0.f, a2 = 0.f, a3 = 0.f;
#define MACI(q) do { a0 = fmaf(BC0(4*q+0), wi##q.x, a0); a1 = fmaf(BC0(4*q+1), wi##q.y, a1); \
                     a2 = fmaf(BC0(4*q+2), wi##q.z, a2); a3 = fmaf(BC0(4*q+3), wi##q.w, a3); } while (0)
#define MACH(q) do { a0 = fmaf(BC1(4*q+0), wh##q.x, a0); a1 = fmaf(BC1(4*q+1), wh##q.y, a1); \
                     a2 = fmaf(BC1(4*q+2), wh##q.z, a2); a3 = fmaf(BC1(4*q+3), wh##q.w, a3); } while (0)
            MACI(0); MACI(1); MACI(2); MACI(3); MACI(4); MACI(5); MACI(6); MACI(7);
            MACI(8); MACI(9); MACI(10); MACI(11); MACI(12); MACI(13); MACI(14); MACI(15);
            MACH(0); MACH(1); MACH(2); MACH(3); MACH(4); MACH(5); MACH(6); MACH(7);
            MACH(8); MACH(9); MACH(10); MACH(11); MACH(12); MACH(13); MACH(14); MACH(15);
#undef MACH
#undef MACI
            lds_b[t & 1][w][lane] = (a0 + a1) + (a2 + a3);
            __syncthreads();   // bar2
            if (tid >= 64 && tid < 128) {   // tail2 (wave1): layer-1 reduce + output
                float s2 = b1v;
                #pragma unroll
                for (int q = 0; q < 8; ++q) s2 += lds_b[t & 1][q][lane];
                const float h1v = tanhx(s2);
                rowbase[(long)t * HH + J] = h1v;                   // THE output (h1 seq)
                if (t + 1 < TT) pub(hbc1 + ((t & 1) << 9) + J, (unsigned)(t + 1), h1v);
                else hTout[(BB << 9) + (c << 9) + J] = h1v;        // hT layer 1
            }
        }
    }
#undef BC1
#undef BC0
}

extern "C" void kernel_launch(void* const* d_in, const int* in_sizes, int n_in,
                              void* d_out, int out_size, void* d_ws, size_t ws_size,
                              hipStream_t stream) {
    const float* x    = (const float*)d_in[0];
    const float* Wih0 = (const float*)d_in[1];
    const float* Whh0 = (const float*)d_in[2];
    const float* b0   = (const float*)d_in[3];
    const float* Wih1 = (const float*)d_in[4];
    const float* Whh1 = (const float*)d_in[5];
    const float* b1   = (const float*)d_in[6];

    float* out = (float*)d_out;                       // [B,T,H] (h1 seq) + [2,B,H] (hT)
    float* hT  = out + (size_t)BB * TT * HH;

    // ws: hb0 [32][2][512]x8B = 256K, hb1 same at +256K. memset both each call:
    // graph replays reuse ws un-poisoned and stale tags would alias wanted tags.
    unsigned long long* hb0 = (unsigned long long*)d_ws;
    unsigned long long* hb1 = hb0 + (size_t)BB * 2 * HH;
    (void)hipMemsetAsync(d_ws, 0, (size_t)2 * BB * 2 * HH * sizeof(unsigned long long), stream);

    // 1) pre0 = x @ W_ih0 + b0  -> d_out main region (consumed in-place by fused_recur)
    ih_gemm<256><<<dim3((BB * TT) / 32), dim3(256), 0, stream>>>(x, Wih0, b0, out);
    // 2) fused 2-layer recurrence: h1 seq -> d_out (in-place over pre0), hT tails
    fused_recur<<<dim3(256), dim3(512), 0, stream>>>(Whh0, Wih1, Whh1, b1,
                                                     out, hT, hb0, hb1);
}